// Round 3
// baseline (219.082 us; speedup 1.0000x reference)
//
#include <hip/hip_runtime.h>
#include <math.h>

#define DM    1024
#define DS    16
#define BB    4
#define LSEQ  2048
#define LOG2E 1.44269504088896f
#define LN2   0.69314718055994f

typedef short bf16x8 __attribute__((ext_vector_type(8)));
typedef float f32x4  __attribute__((ext_vector_type(4)));

__device__ __forceinline__ unsigned short f2bf(float f) {
  unsigned u = __builtin_bit_cast(unsigned, f);
  u += 0x7FFFu + ((u >> 16) & 1u);          // RNE truncate to bf16
  return (unsigned short)(u >> 16);
}
__device__ __forceinline__ float bf2f(unsigned short h) {
  unsigned u = ((unsigned)h) << 16;
  return __builtin_bit_cast(float, u);
}

// ---------------------------------------------------------------------------
// K0: pack Wx (96x1024) and dt_W (1024x64) into hi/lo bf16 pairs (bf16x3 trick)
// ---------------------------------------------------------------------------
__global__ __launch_bounds__(256) void k0_pack(const float* __restrict__ Wx,
                                               const float* __restrict__ dtW,
                                               short* __restrict__ Wxh, short* __restrict__ Wxl,
                                               short* __restrict__ dtWh, short* __restrict__ dtWl) {
  const int i = (blockIdx.x * 256 + threadIdx.x) * 4;   // 163840 total elems
  const float* src; short *dh, *dl; int off;
  if (i < 98304) { src = Wx;  dh = Wxh;  dl = Wxl;  off = i; }
  else           { src = dtW; dh = dtWh; dl = dtWl; off = i - 98304; }
  float4 v = *(const float4*)(src + off);
  float a[4] = {v.x, v.y, v.z, v.w};
  short h4[4], l4[4];
#pragma unroll
  for (int j = 0; j < 4; ++j) {
    unsigned short h = f2bf(a[j]);
    h4[j] = (short)h;
    l4[j] = (short)f2bf(a[j] - bf2f(h));
  }
  *(short4*)(dh + off) = make_short4(h4[0], h4[1], h4[2], h4[3]);
  *(short4*)(dl + off) = make_short4(l4[0], l4[1], l4[2], l4[3]);
}

// ---------------------------------------------------------------------------
// K1: proj = x(8192x1024) @ Wx^T(1024x96) via bf16x3 MFMA. Split-K over the
// block's 4 waves + LDS reduce (no atomics). Epilogue: cols 0..63 -> dt_r
// hi/lo bf16 (feeds k2); cols 64..95 -> BC fp32 (8192x32, feeds scans).
// ---------------------------------------------------------------------------
__global__ __launch_bounds__(256) void k1_proj_mfma(const float* __restrict__ x,
                                                    const short* __restrict__ Wxh,
                                                    const short* __restrict__ Wxl,
                                                    short* __restrict__ dtrh,
                                                    short* __restrict__ dtrl,
                                                    float* __restrict__ BC) {
  __shared__ float red[4][1536];
  const int tid = threadIdx.x, w = tid >> 6, lane = tid & 63;
  const int r0 = blockIdx.x * 16;
  const int m = lane & 15, kj = (lane >> 4) * 8;
  f32x4 acc[6];
#pragma unroll
  for (int nt = 0; nt < 6; ++nt) acc[nt] = (f32x4){0.f, 0.f, 0.f, 0.f};
  const int kb = w * 256;                                // split-K: 256 per wave
  for (int ks = 0; ks < 8; ++ks) {
    const int k = kb + ks * 32 + kj;
    const float* xp = x + (r0 + m) * DM + k;
    float4 a0 = *(const float4*)xp;
    float4 a1 = *(const float4*)(xp + 4);
    float av[8] = {a0.x, a0.y, a0.z, a0.w, a1.x, a1.y, a1.z, a1.w};
    bf16x8 ah, al;
#pragma unroll
    for (int j = 0; j < 8; ++j) {
      unsigned short h = f2bf(av[j]);
      ah[j] = (short)h;
      al[j] = (short)f2bf(av[j] - bf2f(h));
    }
#pragma unroll
    for (int nt = 0; nt < 6; ++nt) {
      const int bo = (nt * 16 + m) * DM + k;
      bf16x8 bh = *(const bf16x8*)(Wxh + bo);
      bf16x8 bl = *(const bf16x8*)(Wxl + bo);
      acc[nt] = __builtin_amdgcn_mfma_f32_16x16x32_bf16(ah, bh, acc[nt], 0, 0, 0);
      acc[nt] = __builtin_amdgcn_mfma_f32_16x16x32_bf16(ah, bl, acc[nt], 0, 0, 0);
      acc[nt] = __builtin_amdgcn_mfma_f32_16x16x32_bf16(al, bh, acc[nt], 0, 0, 0);
    }
  }
#pragma unroll
  for (int nt = 0; nt < 6; ++nt)
    *(f32x4*)&red[w][nt * 256 + lane * 4] = acc[nt];
  __syncthreads();
  const int p = tid;
  const int row = (p >> 6) * 4 + (p & 3), col16 = (p >> 2) & 15;
  const int grow = r0 + row;
#pragma unroll
  for (int nt = 0; nt < 6; ++nt) {
    const float v = red[0][nt * 256 + p] + red[1][nt * 256 + p] +
                    red[2][nt * 256 + p] + red[3][nt * 256 + p];
    if (nt < 4) {
      const int idx = grow * 64 + nt * 16 + col16;
      unsigned short h = f2bf(v);
      dtrh[idx] = (short)h;
      dtrl[idx] = (short)f2bf(v - bf2f(h));
    } else {
      BC[grow * 32 + (nt - 4) * 16 + col16] = v;
    }
  }
}

// ---------------------------------------------------------------------------
// K2: dt = softplus(dt_r(8192x64) @ dt_W^T(64x1024) + b) via bf16x3 MFMA,
//     written to d_out (overwritten in place by y in phase C).
// ---------------------------------------------------------------------------
__global__ __launch_bounds__(256) void k2_dt_mfma(const short* __restrict__ dtrh,
                                                  const short* __restrict__ dtrl,
                                                  const short* __restrict__ dtWh,
                                                  const short* __restrict__ dtWl,
                                                  const float* __restrict__ dt_b,
                                                  float* __restrict__ out) {
  const int tid = threadIdx.x, w = tid >> 6, lane = tid & 63;
  const int r0 = blockIdx.x * 16;
  const int n0 = blockIdx.y * 256 + w * 64;
  const int m = lane & 15, quad = lane >> 4, kj = quad * 8;
  f32x4 acc[4];
#pragma unroll
  for (int nt = 0; nt < 4; ++nt) acc[nt] = (f32x4){0.f, 0.f, 0.f, 0.f};
#pragma unroll
  for (int ks = 0; ks < 2; ++ks) {
    const int k = ks * 32 + kj;
    bf16x8 ah = *(const bf16x8*)(dtrh + (r0 + m) * 64 + k);
    bf16x8 al = *(const bf16x8*)(dtrl + (r0 + m) * 64 + k);
#pragma unroll
    for (int nt = 0; nt < 4; ++nt) {
      const int bo = (n0 + nt * 16 + m) * 64 + k;
      bf16x8 bh = *(const bf16x8*)(dtWh + bo);
      bf16x8 bl = *(const bf16x8*)(dtWl + bo);
      acc[nt] = __builtin_amdgcn_mfma_f32_16x16x32_bf16(ah, bh, acc[nt], 0, 0, 0);
      acc[nt] = __builtin_amdgcn_mfma_f32_16x16x32_bf16(ah, bl, acc[nt], 0, 0, 0);
      acc[nt] = __builtin_amdgcn_mfma_f32_16x16x32_bf16(al, bh, acc[nt], 0, 0, 0);
    }
  }
#pragma unroll
  for (int nt = 0; nt < 4; ++nt) {
    const int col = n0 + nt * 16 + m;
    const float bias = dt_b[col];
#pragma unroll
    for (int i = 0; i < 4; ++i) {
      const float v = acc[nt][i] + bias;
      const float sp = fmaxf(v, 0.f) +
          LN2 * __builtin_amdgcn_logf(1.f + __builtin_amdgcn_exp2f(-LOG2E * fabsf(v)));
      out[(r0 + quad * 4 + i) * DM + col] = sp;
    }
  }
}

// ---------------------------------------------------------------------------
// Phase A: per-chunk local scan (h0=0) -> P (decay product), S (local state).
// B rows staged in LDS once per chunk; dt/x batched G=8 timesteps with
// one-group-ahead prefetch; t-loop NOT unrolled (controls VGPR pressure).
// ---------------------------------------------------------------------------
template <int NC>
__global__ __launch_bounds__(256) void k3_scanA(const float* __restrict__ dtb,
                                                const float* __restrict__ x,
                                                const float* __restrict__ BC,
                                                const float* __restrict__ A_log,
                                                float* __restrict__ Pws,
                                                float* __restrict__ Sws) {
  constexpr int LC = LSEQ / NC;
  constexpr int G = 8, NG = LC / G;
  __shared__ float Bs[LC][16];
  const int tid = threadIdx.x, bid = blockIdx.x;
  const int dblk = bid & 3, c = (bid >> 2) % NC, b = bid / (4 * NC);
  const int d = dblk * 256 + tid;
  const int rowb = b * LSEQ + c * LC;

  // stage B rows for this chunk into LDS (LC*4 float4 loads)
  for (int i = tid; i < LC * 4; i += 256) {
    const int r = i >> 2, q = i & 3;
    *(float4*)&Bs[r][q * 4] = *(const float4*)(BC + (rowb + r) * 32 + q * 4);
  }

  float Aa[DS];
#pragma unroll
  for (int q = 0; q < 4; ++q) {
    float4 v = *(const float4*)(A_log + d * DS + q * 4);
    Aa[q * 4 + 0] = -__expf(v.x) * LOG2E; Aa[q * 4 + 1] = -__expf(v.y) * LOG2E;
    Aa[q * 4 + 2] = -__expf(v.z) * LOG2E; Aa[q * 4 + 3] = -__expf(v.w) * LOG2E;
  }
  float h[DS], Pp[DS];
#pragma unroll
  for (int s = 0; s < DS; ++s) { h[s] = 0.f; Pp[s] = 1.f; }

  float dtc[G], xc[G];
#pragma unroll
  for (int j = 0; j < G; ++j) {
    dtc[j] = dtb[(rowb + j) * DM + d];
    xc[j]  = x[(rowb + j) * DM + d];
  }
  __syncthreads();

#pragma unroll 1
  for (int g = 0; g < NG; ++g) {
    float dtn[G], xn[G];
    const int nb = rowb + ((g + 1 < NG) ? (g + 1) : g) * G;
#pragma unroll
    for (int j = 0; j < G; ++j) {
      dtn[j] = dtb[(nb + j) * DM + d];
      xn[j]  = x[(nb + j) * DM + d];
    }
#pragma unroll
    for (int j = 0; j < G; ++j) {
      const int t = g * G + j;
      float Bv[DS];
#pragma unroll
      for (int q = 0; q < 4; ++q)
        *(float4*)&Bv[q * 4] = *(const float4*)&Bs[t][q * 4];
      const float u = dtc[j] * xc[j];
#pragma unroll
      for (int s = 0; s < DS; ++s) {
        const float dA = __builtin_amdgcn_exp2f(dtc[j] * Aa[s]);
        Pp[s] *= dA;
        h[s] = fmaf(h[s], dA, u * Bv[s]);
      }
    }
#pragma unroll
    for (int j = 0; j < G; ++j) { dtc[j] = dtn[j]; xc[j] = xn[j]; }
  }

  const int base = ((b * NC + c) * DM + d) * DS;
#pragma unroll
  for (int q = 0; q < 4; ++q) {
    *(float4*)(Pws + base + q * 4) = make_float4(Pp[q*4], Pp[q*4+1], Pp[q*4+2], Pp[q*4+3]);
    *(float4*)(Sws + base + q * 4) = make_float4(h[q*4], h[q*4+1], h[q*4+2], h[q*4+3]);
  }
}

// ---------------------------------------------------------------------------
// Phase B: carry combine; batch-8 prefetch breaks the load-latency chain.
// PH = Pws on input, overwritten with Hin (loads precede stores per batch).
// ---------------------------------------------------------------------------
template <int NC>
__global__ __launch_bounds__(256) void k3_comb(float* __restrict__ PH,
                                               const float* __restrict__ Sws) {
  const int t = blockIdx.x * 256 + threadIdx.x;
  const int b = t >> 14, dsi = t & 16383;
  const int cb0 = b * NC;
  float h = 0.f;
#pragma unroll 1
  for (int cb = 0; cb < NC; cb += 8) {
    float p[8], s[8];
#pragma unroll
    for (int j = 0; j < 8; ++j) {
      const int idx = ((cb0 + cb + j) << 14) + dsi;
      p[j] = PH[idx]; s[j] = Sws[idx];
    }
#pragma unroll
    for (int j = 0; j < 8; ++j) {
      const int idx = ((cb0 + cb + j) << 14) + dsi;
      PH[idx] = h;
      h = fmaf(p[j], h, s[j]);
    }
  }
}

// ---------------------------------------------------------------------------
// Phase C: re-scan chunk from Hin carry, y = C.h + x*D in place over dt.
// B and C rows staged in LDS; dt/x batched G=8 with one-group prefetch.
// ---------------------------------------------------------------------------
template <int NC>
__global__ __launch_bounds__(256) void k3_scanC(float* __restrict__ io,
                                                const float* __restrict__ x,
                                                const float* __restrict__ BC,
                                                const float* __restrict__ A_log,
                                                const float* __restrict__ Dvec,
                                                const float* __restrict__ Hin) {
  constexpr int LC = LSEQ / NC;
  constexpr int G = 8, NG = LC / G;
  __shared__ float BCs[LC][32];
  const int tid = threadIdx.x, bid = blockIdx.x;
  const int dblk = bid & 3, c = (bid >> 2) % NC, b = bid / (4 * NC);
  const int d = dblk * 256 + tid;
  const int rowb = b * LSEQ + c * LC;

  // stage B and C rows for this chunk (LC*8 float4 loads)
  for (int i = tid; i < LC * 8; i += 256) {
    const int r = i >> 3, q = i & 7;
    *(float4*)&BCs[r][q * 4] = *(const float4*)(BC + (rowb + r) * 32 + q * 4);
  }

  float Aa[DS];
#pragma unroll
  for (int q = 0; q < 4; ++q) {
    float4 v = *(const float4*)(A_log + d * DS + q * 4);
    Aa[q * 4 + 0] = -__expf(v.x) * LOG2E; Aa[q * 4 + 1] = -__expf(v.y) * LOG2E;
    Aa[q * 4 + 2] = -__expf(v.z) * LOG2E; Aa[q * 4 + 3] = -__expf(v.w) * LOG2E;
  }
  float h[DS];
  const int base = ((b * NC + c) * DM + d) * DS;
#pragma unroll
  for (int q = 0; q < 4; ++q)
    *(float4*)&h[q * 4] = *(const float4*)(Hin + base + q * 4);
  const float Dv = Dvec[d];

  float dtc[G], xc[G];
#pragma unroll
  for (int j = 0; j < G; ++j) {
    dtc[j] = io[(rowb + j) * DM + d];
    xc[j]  = x[(rowb + j) * DM + d];
  }
  __syncthreads();

#pragma unroll 1
  for (int g = 0; g < NG; ++g) {
    float dtn[G], xn[G];
    const int nb = rowb + ((g + 1 < NG) ? (g + 1) : g) * G;
#pragma unroll
    for (int j = 0; j < G; ++j) {
      dtn[j] = io[(nb + j) * DM + d];
      xn[j]  = x[(nb + j) * DM + d];
    }
#pragma unroll
    for (int j = 0; j < G; ++j) {
      const int t = g * G + j;
      float Bv[DS], Cv[DS];
#pragma unroll
      for (int q = 0; q < 4; ++q) {
        *(float4*)&Bv[q * 4] = *(const float4*)&BCs[t][q * 4];
        *(float4*)&Cv[q * 4] = *(const float4*)&BCs[t][16 + q * 4];
      }
      const float u = dtc[j] * xc[j];
      float y = 0.f;
#pragma unroll
      for (int s = 0; s < DS; ++s) {
        const float dA = __builtin_amdgcn_exp2f(dtc[j] * Aa[s]);
        h[s] = fmaf(h[s], dA, u * Bv[s]);
        y = fmaf(h[s], Cv[s], y);
      }
      io[(rowb + t) * DM + d] = fmaf(xc[j], Dv, y);
    }
#pragma unroll
    for (int j = 0; j < G; ++j) { dtc[j] = dtn[j]; xc[j] = xn[j]; }
  }
}

// ---------------------------------------------------------------------------
// ws layout (shorts then floats):
//   Wxh/Wxl 98304 ea | dtWh/dtWl 65536 ea | dtrh/dtrl 524288 ea  (= 688128 floats)
//   BC 262144 f | P (NC*65536 f, becomes Hin) | S (NC*65536 f)
// ---------------------------------------------------------------------------
extern "C" void kernel_launch(void* const* d_in, const int* in_sizes, int n_in,
                              void* d_out, int out_size, void* d_ws, size_t ws_size,
                              hipStream_t stream) {
  const float* x     = (const float*)d_in[0];
  const float* A_log = (const float*)d_in[1];
  const float* Dvec  = (const float*)d_in[2];
  const float* Wx    = (const float*)d_in[3];
  const float* dt_W  = (const float*)d_in[4];
  const float* dt_b  = (const float*)d_in[5];
  float* out = (float*)d_out;
  float* ws  = (float*)d_ws;

  short* Wxh  = (short*)ws;
  short* Wxl  = Wxh + 98304;
  short* dtWh = Wxl + 98304;
  short* dtWl = dtWh + 65536;
  short* dtrh = dtWl + 65536;
  short* dtrl = dtrh + 524288;
  float* BC   = ws + 688128;
  float* P    = BC + 262144;           // re-used as Hin by k3_comb

  k0_pack<<<160, 256, 0, stream>>>(Wx, dt_W, Wxh, Wxl, dtWh, dtWl);
  k1_proj_mfma<<<512, 256, 0, stream>>>(x, Wxh, Wxl, dtrh, dtrl, BC);
  k2_dt_mfma<<<dim3(512, 4), 256, 0, stream>>>(dtrh, dtrl, dtWh, dtWl, dt_b, out);

  if (ws_size >= (size_t)(950272 + 2 * 64 * 65536) * 4) {
    constexpr int NC = 64;
    float* S = P + NC * 65536;
    k3_scanA<NC><<<BB * NC * 4, 256, 0, stream>>>(out, x, BC, A_log, P, S);
    k3_comb<NC><<<256, 256, 0, stream>>>(P, S);
    k3_scanC<NC><<<BB * NC * 4, 256, 0, stream>>>(out, x, BC, A_log, Dvec, P);
  } else {
    constexpr int NC = 32;
    float* S = P + NC * 65536;
    k3_scanA<NC><<<BB * NC * 4, 256, 0, stream>>>(out, x, BC, A_log, P, S);
    k3_comb<NC><<<256, 256, 0, stream>>>(P, S);
    k3_scanC<NC><<<BB * NC * 4, 256, 0, stream>>>(out, x, BC, A_log, Dvec, P);
  }
}

// Round 4
// 205.062 us; speedup vs baseline: 1.0684x; 1.0684x over previous
//
#include <hip/hip_runtime.h>
#include <math.h>

#define DM    1024
#define DS    16
#define BB    4
#define LSEQ  2048
#define LOG2E 1.44269504088896f
#define LN2   0.69314718055994f

typedef short bf16x8 __attribute__((ext_vector_type(8)));
typedef float f32x4  __attribute__((ext_vector_type(4)));

__device__ __forceinline__ unsigned short f2bf(float f) {
  unsigned u = __builtin_bit_cast(unsigned, f);
  u += 0x7FFFu + ((u >> 16) & 1u);          // RNE truncate to bf16
  return (unsigned short)(u >> 16);
}
__device__ __forceinline__ float bf2f(unsigned short h) {
  unsigned u = ((unsigned)h) << 16;
  return __builtin_bit_cast(float, u);
}

// ---------------------------------------------------------------------------
// K0: pack Wx (96x1024) and dt_W (1024x64) into hi/lo bf16 pairs (bf16x3 trick)
// ---------------------------------------------------------------------------
__global__ __launch_bounds__(256) void k0_pack(const float* __restrict__ Wx,
                                               const float* __restrict__ dtW,
                                               short* __restrict__ Wxh, short* __restrict__ Wxl,
                                               short* __restrict__ dtWh, short* __restrict__ dtWl) {
  const int i = (blockIdx.x * 256 + threadIdx.x) * 4;   // 163840 total elems
  const float* src; short *dh, *dl; int off;
  if (i < 98304) { src = Wx;  dh = Wxh;  dl = Wxl;  off = i; }
  else           { src = dtW; dh = dtWh; dl = dtWl; off = i - 98304; }
  float4 v = *(const float4*)(src + off);
  float a[4] = {v.x, v.y, v.z, v.w};
  short h4[4], l4[4];
#pragma unroll
  for (int j = 0; j < 4; ++j) {
    unsigned short h = f2bf(a[j]);
    h4[j] = (short)h;
    l4[j] = (short)f2bf(a[j] - bf2f(h));
  }
  *(short4*)(dh + off) = make_short4(h4[0], h4[1], h4[2], h4[3]);
  *(short4*)(dl + off) = make_short4(l4[0], l4[1], l4[2], l4[3]);
}

// ---------------------------------------------------------------------------
// K1: proj = x(8192x1024) @ Wx^T(1024x96) via bf16x3 MFMA. Split-K over the
// block's 4 waves + LDS reduce. Epilogue: cols 0..63 -> dt_r hi/lo bf16,
// cols 64..95 -> BC fp32 (8192x32).
// ---------------------------------------------------------------------------
__global__ __launch_bounds__(256) void k1_proj_mfma(const float* __restrict__ x,
                                                    const short* __restrict__ Wxh,
                                                    const short* __restrict__ Wxl,
                                                    short* __restrict__ dtrh,
                                                    short* __restrict__ dtrl,
                                                    float* __restrict__ BC) {
  __shared__ float red[4][1536];
  const int tid = threadIdx.x, w = tid >> 6, lane = tid & 63;
  const int r0 = blockIdx.x * 16;
  const int m = lane & 15, kj = (lane >> 4) * 8;
  f32x4 acc[6];
#pragma unroll
  for (int nt = 0; nt < 6; ++nt) acc[nt] = (f32x4){0.f, 0.f, 0.f, 0.f};
  const int kb = w * 256;                                // split-K: 256 per wave
  for (int ks = 0; ks < 8; ++ks) {
    const int k = kb + ks * 32 + kj;
    const float* xp = x + (r0 + m) * DM + k;
    float4 a0 = *(const float4*)xp;
    float4 a1 = *(const float4*)(xp + 4);
    float av[8] = {a0.x, a0.y, a0.z, a0.w, a1.x, a1.y, a1.z, a1.w};
    bf16x8 ah, al;
#pragma unroll
    for (int j = 0; j < 8; ++j) {
      unsigned short h = f2bf(av[j]);
      ah[j] = (short)h;
      al[j] = (short)f2bf(av[j] - bf2f(h));
    }
#pragma unroll
    for (int nt = 0; nt < 6; ++nt) {
      const int bo = (nt * 16 + m) * DM + k;
      bf16x8 bh = *(const bf16x8*)(Wxh + bo);
      bf16x8 bl = *(const bf16x8*)(Wxl + bo);
      acc[nt] = __builtin_amdgcn_mfma_f32_16x16x32_bf16(ah, bh, acc[nt], 0, 0, 0);
      acc[nt] = __builtin_amdgcn_mfma_f32_16x16x32_bf16(ah, bl, acc[nt], 0, 0, 0);
      acc[nt] = __builtin_amdgcn_mfma_f32_16x16x32_bf16(al, bh, acc[nt], 0, 0, 0);
    }
  }
#pragma unroll
  for (int nt = 0; nt < 6; ++nt)
    *(f32x4*)&red[w][nt * 256 + lane * 4] = acc[nt];
  __syncthreads();
  const int p = tid;
  const int row = (p >> 6) * 4 + (p & 3), col16 = (p >> 2) & 15;
  const int grow = r0 + row;
#pragma unroll
  for (int nt = 0; nt < 6; ++nt) {
    const float v = red[0][nt * 256 + p] + red[1][nt * 256 + p] +
                    red[2][nt * 256 + p] + red[3][nt * 256 + p];
    if (nt < 4) {
      const int idx = grow * 64 + nt * 16 + col16;
      unsigned short h = f2bf(v);
      dtrh[idx] = (short)h;
      dtrl[idx] = (short)f2bf(v - bf2f(h));
    } else {
      BC[grow * 32 + (nt - 4) * 16 + col16] = v;
    }
  }
}

// ---------------------------------------------------------------------------
// K2: dt = softplus(dt_r(8192x64) @ dt_W^T(64x1024) + b) via bf16x3 MFMA,
//     written to d_out (overwritten in place by y in phase C).
// ---------------------------------------------------------------------------
__global__ __launch_bounds__(256) void k2_dt_mfma(const short* __restrict__ dtrh,
                                                  const short* __restrict__ dtrl,
                                                  const short* __restrict__ dtWh,
                                                  const short* __restrict__ dtWl,
                                                  const float* __restrict__ dt_b,
                                                  float* __restrict__ out) {
  const int tid = threadIdx.x, w = tid >> 6, lane = tid & 63;
  const int r0 = blockIdx.x * 16;
  const int n0 = blockIdx.y * 256 + w * 64;
  const int m = lane & 15, quad = lane >> 4, kj = quad * 8;
  f32x4 acc[4];
#pragma unroll
  for (int nt = 0; nt < 4; ++nt) acc[nt] = (f32x4){0.f, 0.f, 0.f, 0.f};
#pragma unroll
  for (int ks = 0; ks < 2; ++ks) {
    const int k = ks * 32 + kj;
    bf16x8 ah = *(const bf16x8*)(dtrh + (r0 + m) * 64 + k);
    bf16x8 al = *(const bf16x8*)(dtrl + (r0 + m) * 64 + k);
#pragma unroll
    for (int nt = 0; nt < 4; ++nt) {
      const int bo = (n0 + nt * 16 + m) * 64 + k;
      bf16x8 bh = *(const bf16x8*)(dtWh + bo);
      bf16x8 bl = *(const bf16x8*)(dtWl + bo);
      acc[nt] = __builtin_amdgcn_mfma_f32_16x16x32_bf16(ah, bh, acc[nt], 0, 0, 0);
      acc[nt] = __builtin_amdgcn_mfma_f32_16x16x32_bf16(ah, bl, acc[nt], 0, 0, 0);
      acc[nt] = __builtin_amdgcn_mfma_f32_16x16x32_bf16(al, bh, acc[nt], 0, 0, 0);
    }
  }
#pragma unroll
  for (int nt = 0; nt < 4; ++nt) {
    const int col = n0 + nt * 16 + m;
    const float bias = dt_b[col];
#pragma unroll
    for (int i = 0; i < 4; ++i) {
      const float v = acc[nt][i] + bias;
      const float sp = fmaxf(v, 0.f) +
          LN2 * __builtin_amdgcn_logf(1.f + __builtin_amdgcn_exp2f(-LOG2E * fabsf(v)));
      out[(r0 + quad * 4 + i) * DM + col] = sp;
    }
  }
}

// ---------------------------------------------------------------------------
// Phase A: per-chunk local scan (h0=0) -> P (decay product), S (local state).
// B rows in LDS, software-pipelined one step ahead into registers (Bn).
// P computed analytically: P[s] = exp2(Aa[s] * sum(dt)).
// ---------------------------------------------------------------------------
template <int NC>
__global__ __launch_bounds__(256, 4) void k3_scanA(const float* __restrict__ dtb,
                                                   const float* __restrict__ x,
                                                   const float* __restrict__ BC,
                                                   const float* __restrict__ A_log,
                                                   float* __restrict__ Pws,
                                                   float* __restrict__ Sws) {
  constexpr int LC = LSEQ / NC;
  constexpr int G = 8, NG = LC / G;
  __shared__ float Bs[LC][16];
  const int tid = threadIdx.x, bid = blockIdx.x;
  const int dblk = bid & 3, c = (bid >> 2) % NC, b = bid / (4 * NC);
  const int d = dblk * 256 + tid;
  const int rowb = b * LSEQ + c * LC;

  for (int i = tid; i < LC * 4; i += 256) {
    const int r = i >> 2, q = i & 3;
    *(float4*)&Bs[r][q * 4] = *(const float4*)(BC + (rowb + r) * 32 + q * 4);
  }

  float Aa[DS];
#pragma unroll
  for (int q = 0; q < 4; ++q) {
    float4 v = *(const float4*)(A_log + d * DS + q * 4);
    Aa[q * 4 + 0] = -__expf(v.x) * LOG2E; Aa[q * 4 + 1] = -__expf(v.y) * LOG2E;
    Aa[q * 4 + 2] = -__expf(v.z) * LOG2E; Aa[q * 4 + 3] = -__expf(v.w) * LOG2E;
  }
  float h[DS];
#pragma unroll
  for (int s = 0; s < DS; ++s) h[s] = 0.f;
  float sdt = 0.f;

  float dtc[G], xc[G];
#pragma unroll
  for (int j = 0; j < G; ++j) {
    dtc[j] = dtb[(rowb + j) * DM + d];
    xc[j]  = x[(rowb + j) * DM + d];
  }
  __syncthreads();

  float Bn[DS];
#pragma unroll
  for (int q = 0; q < 4; ++q)
    *(float4*)&Bn[q * 4] = *(const float4*)&Bs[0][q * 4];

#pragma unroll 1
  for (int g = 0; g < NG; ++g) {
    float dtn[G], xn[G];
    const int nb = rowb + ((g + 1 < NG) ? (g + 1) : g) * G;
#pragma unroll
    for (int j = 0; j < G; ++j) {
      dtn[j] = dtb[(nb + j) * DM + d];
      xn[j]  = x[(nb + j) * DM + d];
    }
#pragma unroll
    for (int j = 0; j < G; ++j) {
      const int t = g * G + j;
      float Bv[DS];
#pragma unroll
      for (int s = 0; s < DS; ++s) Bv[s] = Bn[s];
      const int t1 = (t + 1) & (LC - 1);          // wrap at end: value unused
#pragma unroll
      for (int q = 0; q < 4; ++q)
        *(float4*)&Bn[q * 4] = *(const float4*)&Bs[t1][q * 4];
      const float u = dtc[j] * xc[j];
      sdt += dtc[j];
#pragma unroll
      for (int s = 0; s < DS; ++s) {
        const float dA = __builtin_amdgcn_exp2f(dtc[j] * Aa[s]);
        h[s] = fmaf(h[s], dA, u * Bv[s]);
      }
    }
#pragma unroll
    for (int j = 0; j < G; ++j) { dtc[j] = dtn[j]; xc[j] = xn[j]; }
  }

  const int base = ((b * NC + c) * DM + d) * DS;
#pragma unroll
  for (int q = 0; q < 4; ++q) {
    float4 pv;
    pv.x = __builtin_amdgcn_exp2f(Aa[q * 4 + 0] * sdt);
    pv.y = __builtin_amdgcn_exp2f(Aa[q * 4 + 1] * sdt);
    pv.z = __builtin_amdgcn_exp2f(Aa[q * 4 + 2] * sdt);
    pv.w = __builtin_amdgcn_exp2f(Aa[q * 4 + 3] * sdt);
    *(float4*)(Pws + base + q * 4) = pv;
    *(float4*)(Sws + base + q * 4) = make_float4(h[q*4], h[q*4+1], h[q*4+2], h[q*4+3]);
  }
}

// ---------------------------------------------------------------------------
// Phase B: carry combine; batch-8 prefetch breaks the load-latency chain.
// PH = Pws on input, overwritten with Hin (loads precede stores per batch).
// ---------------------------------------------------------------------------
template <int NC>
__global__ __launch_bounds__(256) void k3_comb(float* __restrict__ PH,
                                               const float* __restrict__ Sws) {
  const int t = blockIdx.x * 256 + threadIdx.x;
  const int b = t >> 14, dsi = t & 16383;
  const int cb0 = b * NC;
  float h = 0.f;
#pragma unroll 1
  for (int cb = 0; cb < NC; cb += 8) {
    float p[8], s[8];
#pragma unroll
    for (int j = 0; j < 8; ++j) {
      const int idx = ((cb0 + cb + j) << 14) + dsi;
      p[j] = PH[idx]; s[j] = Sws[idx];
    }
#pragma unroll
    for (int j = 0; j < 8; ++j) {
      const int idx = ((cb0 + cb + j) << 14) + dsi;
      PH[idx] = h;
      h = fmaf(p[j], h, s[j]);
    }
  }
}

// ---------------------------------------------------------------------------
// Phase C: re-scan chunk from Hin carry, y = C.h + x*D in place over dt.
// B/C rows in LDS, pipelined one step ahead (Bn/Cn). G=4 keeps VGPR <= 128.
// ---------------------------------------------------------------------------
template <int NC>
__global__ __launch_bounds__(256, 4) void k3_scanC(float* __restrict__ io,
                                                   const float* __restrict__ x,
                                                   const float* __restrict__ BC,
                                                   const float* __restrict__ A_log,
                                                   const float* __restrict__ Dvec,
                                                   const float* __restrict__ Hin) {
  constexpr int LC = LSEQ / NC;
  constexpr int G = 4, NG = LC / G;
  __shared__ float BCs[LC][32];
  const int tid = threadIdx.x, bid = blockIdx.x;
  const int dblk = bid & 3, c = (bid >> 2) % NC, b = bid / (4 * NC);
  const int d = dblk * 256 + tid;
  const int rowb = b * LSEQ + c * LC;

  for (int i = tid; i < LC * 8; i += 256) {
    const int r = i >> 3, q = i & 7;
    *(float4*)&BCs[r][q * 4] = *(const float4*)(BC + (rowb + r) * 32 + q * 4);
  }

  float Aa[DS];
#pragma unroll
  for (int q = 0; q < 4; ++q) {
    float4 v = *(const float4*)(A_log + d * DS + q * 4);
    Aa[q * 4 + 0] = -__expf(v.x) * LOG2E; Aa[q * 4 + 1] = -__expf(v.y) * LOG2E;
    Aa[q * 4 + 2] = -__expf(v.z) * LOG2E; Aa[q * 4 + 3] = -__expf(v.w) * LOG2E;
  }
  float h[DS];
  const int base = ((b * NC + c) * DM + d) * DS;
#pragma unroll
  for (int q = 0; q < 4; ++q)
    *(float4*)&h[q * 4] = *(const float4*)(Hin + base + q * 4);
  const float Dv = Dvec[d];

  float dtc[G], xc[G];
#pragma unroll
  for (int j = 0; j < G; ++j) {
    dtc[j] = io[(rowb + j) * DM + d];
    xc[j]  = x[(rowb + j) * DM + d];
  }
  __syncthreads();

  float Bn[DS], Cn[DS];
#pragma unroll
  for (int q = 0; q < 4; ++q) {
    *(float4*)&Bn[q * 4] = *(const float4*)&BCs[0][q * 4];
    *(float4*)&Cn[q * 4] = *(const float4*)&BCs[0][16 + q * 4];
  }

#pragma unroll 1
  for (int g = 0; g < NG; ++g) {
    float dtn[G], xn[G];
    const int nb = rowb + ((g + 1 < NG) ? (g + 1) : g) * G;
#pragma unroll
    for (int j = 0; j < G; ++j) {
      dtn[j] = io[(nb + j) * DM + d];
      xn[j]  = x[(nb + j) * DM + d];
    }
#pragma unroll
    for (int j = 0; j < G; ++j) {
      const int t = g * G + j;
      float Bv[DS], Cv[DS];
#pragma unroll
      for (int s = 0; s < DS; ++s) { Bv[s] = Bn[s]; Cv[s] = Cn[s]; }
      const int t1 = (t + 1) & (LC - 1);          // wrap at end: value unused
#pragma unroll
      for (int q = 0; q < 4; ++q) {
        *(float4*)&Bn[q * 4] = *(const float4*)&BCs[t1][q * 4];
        *(float4*)&Cn[q * 4] = *(const float4*)&BCs[t1][16 + q * 4];
      }
      const float u = dtc[j] * xc[j];
      float y = 0.f;
#pragma unroll
      for (int s = 0; s < DS; ++s) {
        const float dA = __builtin_amdgcn_exp2f(dtc[j] * Aa[s]);
        h[s] = fmaf(h[s], dA, u * Bv[s]);
        y = fmaf(h[s], Cv[s], y);
      }
      io[(rowb + t) * DM + d] = fmaf(xc[j], Dv, y);
    }
#pragma unroll
    for (int j = 0; j < G; ++j) { dtc[j] = dtn[j]; xc[j] = xn[j]; }
  }
}

// ---------------------------------------------------------------------------
// ws layout (shorts then floats):
//   Wxh/Wxl 98304 ea | dtWh/dtWl 65536 ea | dtrh/dtrl 524288 ea  (= 688128 floats)
//   BC 262144 f | P (NC*65536 f, becomes Hin) | S (NC*65536 f)
// ---------------------------------------------------------------------------
extern "C" void kernel_launch(void* const* d_in, const int* in_sizes, int n_in,
                              void* d_out, int out_size, void* d_ws, size_t ws_size,
                              hipStream_t stream) {
  const float* x     = (const float*)d_in[0];
  const float* A_log = (const float*)d_in[1];
  const float* Dvec  = (const float*)d_in[2];
  const float* Wx    = (const float*)d_in[3];
  const float* dt_W  = (const float*)d_in[4];
  const float* dt_b  = (const float*)d_in[5];
  float* out = (float*)d_out;
  float* ws  = (float*)d_ws;

  short* Wxh  = (short*)ws;
  short* Wxl  = Wxh + 98304;
  short* dtWh = Wxl + 98304;
  short* dtWl = dtWh + 65536;
  short* dtrh = dtWl + 65536;
  short* dtrl = dtrh + 524288;
  float* BC   = ws + 688128;
  float* P    = BC + 262144;           // re-used as Hin by k3_comb

  k0_pack<<<160, 256, 0, stream>>>(Wx, dt_W, Wxh, Wxl, dtWh, dtWl);
  k1_proj_mfma<<<512, 256, 0, stream>>>(x, Wxh, Wxl, dtrh, dtrl, BC);
  k2_dt_mfma<<<dim3(512, 4), 256, 0, stream>>>(dtrh, dtrl, dtWh, dtWl, dt_b, out);

  if (ws_size >= (size_t)(950272 + 2 * 64 * 65536) * 4) {
    constexpr int NC = 64;
    float* S = P + NC * 65536;
    k3_scanA<NC><<<BB * NC * 4, 256, 0, stream>>>(out, x, BC, A_log, P, S);
    k3_comb<NC><<<256, 256, 0, stream>>>(P, S);
    k3_scanC<NC><<<BB * NC * 4, 256, 0, stream>>>(out, x, BC, A_log, Dvec, P);
  } else {
    constexpr int NC = 32;
    float* S = P + NC * 65536;
    k3_scanA<NC><<<BB * NC * 4, 256, 0, stream>>>(out, x, BC, A_log, P, S);
    k3_comb<NC><<<256, 256, 0, stream>>>(P, S);
    k3_scanC<NC><<<BB * NC * 4, 256, 0, stream>>>(out, x, BC, A_log, Dvec, P);
  }
}